// Round 1
// baseline (257.584 us; speedup 1.0000x reference)
//
#include <hip/hip_runtime.h>
#include <cstdint>
#include <cstddef>

// Problem: B=64, R=196, L=512, K=768.
// Key algebra: emb = p @ q^T + q^T = (1+p) outer q  ==>
//   score[b,r,j] = (1+p[b,r]) * w[b,j],  w[b,:] = q[b,:] @ V
// softmax rows share one masked vector wm[b,:], scaled by c_r = 1+p[b,r].
// out[b,r,:] = (1/Z_r) * sum_j exp(c_r*wm_j - M_r) * seq_emb[b,j,:] / sqrt(768)

typedef __attribute__((ext_vector_type(8))) short short8;
typedef __attribute__((ext_vector_type(4))) float f32x4;

__device__ __forceinline__ unsigned short f32_to_bf16(float x) {
    unsigned int u = __float_as_uint(x);
    unsigned int r = (u + 0x7FFFu + ((u >> 16) & 1u)) >> 16;  // RNE
    return (unsigned short)r;
}
__device__ __forceinline__ float bf16_to_f32(unsigned short h) {
    return __uint_as_float(((unsigned int)h) << 16);
}

// ---------------- kernel 1: p[row] = tanh(image_emb[row,:512] . image_W) ----
__global__ __launch_bounds__(256) void krows_p(const float* __restrict__ x,
                                               const float* __restrict__ w,
                                               const float* __restrict__ bias,
                                               float* __restrict__ outp) {
    int wv = threadIdx.x >> 6, lane = threadIdx.x & 63;
    int row = blockIdx.x * 4 + wv;                    // 12544 rows
    const float4* x4 = (const float4*)(x + (size_t)row * 512);
    const float4* w4 = (const float4*)w;
    float s = 0.f;
#pragma unroll
    for (int i = 0; i < 2; ++i) {
        float4 a = x4[i * 64 + lane];
        float4 c = w4[i * 64 + lane];
        s += a.x * c.x + a.y * c.y + a.z * c.z + a.w * c.w;
    }
#pragma unroll
    for (int o = 32; o; o >>= 1) s += __shfl_xor(s, o, 64);
    if (lane == 0) outp[row] = tanhf(s + bias[0]);
}

// ---------------- kernel 2: q[row] = tanh(seq_emb[row,:768] . seq_W) --------
__global__ __launch_bounds__(256) void krows_q(const float* __restrict__ x,
                                               const float* __restrict__ w,
                                               const float* __restrict__ bias,
                                               float* __restrict__ outp) {
    int wv = threadIdx.x >> 6, lane = threadIdx.x & 63;
    int row = blockIdx.x * 4 + wv;                    // 32768 rows
    const float4* x4 = (const float4*)(x + (size_t)row * 768);
    const float4* w4 = (const float4*)w;
    float s = 0.f;
#pragma unroll
    for (int i = 0; i < 3; ++i) {
        float4 a = x4[i * 64 + lane];
        float4 c = w4[i * 64 + lane];
        s += a.x * c.x + a.y * c.y + a.z * c.z + a.w * c.w;
    }
#pragma unroll
    for (int o = 32; o; o >>= 1) s += __shfl_xor(s, o, 64);
    if (lane == 0) outp[row] = tanhf(s + bias[0]);
}

// ------- kernel 3: wm[b,j] = mask[b,j] ? (q[b,:] @ V[:,j]) : -1e30 ----------
// grid = 256 blocks: (b, jc) with jc = 128-wide column chunk of V
__global__ __launch_bounds__(256) void kw(const float* __restrict__ qv,
                                          const float* __restrict__ V,
                                          const int* __restrict__ mask,
                                          float* __restrict__ wm) {
    __shared__ __align__(16) float sq[512];
    __shared__ __align__(16) float sacc[8][32][4];
    int b = blockIdx.x >> 2, jc = blockIdx.x & 3;
    int t = threadIdx.x;
    sq[t] = qv[b * 512 + t];
    sq[t + 256] = qv[b * 512 + t + 256];
    __syncthreads();
    int jt = t & 31, lg = t >> 5;                     // 32 j-threads x 8 l-groups
    const float4* V4 = (const float4*)V;              // row stride = 128 float4
    int col4 = jc * 32 + jt;
    float ax = 0.f, ay = 0.f, az = 0.f, aw = 0.f;
    int lbase = lg * 64;
#pragma unroll 8
    for (int li = 0; li < 64; ++li) {
        int l = lbase + li;
        float qq = sq[l];
        float4 v = V4[(size_t)l * 128 + col4];
        ax += qq * v.x; ay += qq * v.y; az += qq * v.z; aw += qq * v.w;
    }
    sacc[lg][jt][0] = ax; sacc[lg][jt][1] = ay;
    sacc[lg][jt][2] = az; sacc[lg][jt][3] = aw;
    __syncthreads();
    if (t < 32) {
        float sx = 0.f, sy = 0.f, sz = 0.f, sw = 0.f;
#pragma unroll
        for (int g = 0; g < 8; ++g) {
            sx += sacc[g][t][0]; sy += sacc[g][t][1];
            sz += sacc[g][t][2]; sw += sacc[g][t][3];
        }
        const int* mrow = mask + b * 512 + jc * 128 + t * 4;
        float4 o;
        o.x = mrow[0] ? sx : -1e30f;
        o.y = mrow[1] ? sy : -1e30f;
        o.z = mrow[2] ? sz : -1e30f;
        o.w = mrow[3] ? sw : -1e30f;
        ((float4*)(wm + b * 512 + jc * 128))[t] = o;
    }
}

// ------- kernel 4: fused scaled-softmax + (alpha @ seq_emb) via bf16 MFMA ---
// grid = 64b * 4rt * 6nt = 1536 blocks, 256 threads (4 waves).
// Tile: M=64 (r), N=128 (k), full L=512 reduction. A-fragments (alpha-hat,
// unnormalized) live in registers; seq staged fp32->bf16 transposed [n][j]
// in LDS with XOR swizzle; 1/Z and 1/sqrt(768) applied in epilogue.
__global__ __launch_bounds__(256, 2) void kattn(const float* __restrict__ seq,
                                                const float* __restrict__ p,
                                                const float* __restrict__ wm,
                                                float* __restrict__ out) {
    __shared__ __align__(16) unsigned int sseq[2][128 * 32];  // 2 x 16 KB
    __shared__ __align__(16) float swm[512];
    __shared__ float sinvz[64];
    __shared__ float sred[16];

    int id = blockIdx.x;
    int rt = id & 3;
    int nt = (id >> 2) % 6;
    int b  = id / 24;
    int t  = threadIdx.x;
    int wv = t >> 6, lane = t & 63;
    int mm = lane & 15, q = lane >> 4;
    int nb = nt * 128;

    // --- phase 0a: wm -> LDS, block max/min over unmasked ---
    float v0 = wm[b * 512 + t];
    float v1 = wm[b * 512 + t + 256];
    swm[t] = v0; swm[t + 256] = v1;
    float lmax = fmaxf(v0, v1);
    float fa = (v0 > -1e29f) ? v0 : 1e30f;
    float fb = (v1 > -1e29f) ? v1 : 1e30f;
    float lmin = fminf(fa, fb);
#pragma unroll
    for (int o = 32; o; o >>= 1) {
        lmax = fmaxf(lmax, __shfl_xor(lmax, o, 64));
        lmin = fminf(lmin, __shfl_xor(lmin, o, 64));
    }
    if (lane == 0) { sred[wv] = lmax; sred[8 + wv] = lmin; }
    __syncthreads();
    float wmax = fmaxf(fmaxf(sred[0], sred[1]), fmaxf(sred[2], sred[3]));
    float wmin = fminf(fminf(sred[8], sred[9]), fminf(sred[10], sred[11]));

    // --- per-row softmax params (row for A-fragment = wv*16 + mm) ---
    int rl = wv * 16 + mm;
    int r  = rt * 64 + rl;
    bool valid = r < 196;
    int pidx = b * 196 + (valid ? r : 195);
    float c = 1.0f + p[pidx];
    float M = (c >= 0.f) ? c * wmax : c * wmin;   // c>0 always, keep select

    // --- phase 0b: alpha-hat A-fragments in registers + Z ---
    short8 afrag[16];
    float zsum = 0.f;
    const f32x4* swm4 = (const f32x4*)swm;
#pragma unroll
    for (int tk = 0; tk < 16; ++tk) {
        int jb = tk * 32 + q * 8;                 // lane's 8 k's this kstep
        f32x4 w0 = swm4[jb >> 2];
        f32x4 w1 = swm4[(jb >> 2) + 1];
        short8 af;
#pragma unroll
        for (int jj = 0; jj < 8; ++jj) {
            float ww = (jj < 4) ? w0[jj] : w1[jj - 4];
            float e = valid ? __expf(c * ww - M) : 0.f;   // e in [0,1]
            unsigned short h = f32_to_bf16(e);
            zsum += bf16_to_f32(h);               // Z consistent with bf16 alpha
            af[jj] = (short)h;
        }
        afrag[tk] = af;
    }
    zsum += __shfl_xor(zsum, 16, 64);
    zsum += __shfl_xor(zsum, 32, 64);
    if (q == 0) sinvz[rl] = 1.0f / zsum;

    f32x4 acc[8];
#pragma unroll
    for (int s = 0; s < 8; ++s) acc[s] = (f32x4){0.f, 0.f, 0.f, 0.f};

    // --- staging: seq[b, ch*64+jl, nb+n] -> bf16, transposed [n][jl], XOR swz
    const float* seqb = seq + (size_t)b * 512 * 768 + nb;
    int tl = t & 31, jp = t >> 5;
    int n0 = tl * 4;
    auto stage = [&](int ch, int buf) {
        unsigned int* sb = sseq[buf];
#pragma unroll
        for (int pass = 0; pass < 4; ++pass) {
            int jl = pass * 16 + jp * 2;          // even
            int jglob = ch * 64 + jl;
            float4 a0 = *(const float4*)(seqb + (size_t)jglob * 768 + n0);
            float4 a1 = *(const float4*)(seqb + (size_t)(jglob + 1) * 768 + n0);
            float a0v[4] = {a0.x, a0.y, a0.z, a0.w};
            float a1v[4] = {a1.x, a1.y, a1.z, a1.w};
            int g = jl >> 3;
            int wo = (jl & 7) >> 1;
#pragma unroll
            for (int i = 0; i < 4; ++i) {
                int n = n0 + i;
                int sw = (n ^ (n >> 3)) & 7;
                unsigned int pk = (unsigned int)f32_to_bf16(a0v[i]) |
                                  ((unsigned int)f32_to_bf16(a1v[i]) << 16);
                sb[n * 32 + ((g ^ sw) << 2) + wo] = pk;
            }
        }
    };

    __syncthreads();
    stage(0, 0);
    __syncthreads();
#pragma unroll
    for (int ch = 0; ch < 8; ++ch) {
        if (ch < 7) stage(ch + 1, (ch + 1) & 1);
        const unsigned int* cb = sseq[ch & 1];
#pragma unroll
        for (int kk = 0; kk < 2; ++kk) {
            short8 bfr[8];
#pragma unroll
            for (int s = 0; s < 8; ++s) {
                int n = s * 16 + mm;
                int g = kk * 4 + q;
                int sw = (n ^ (n >> 3)) & 7;
                bfr[s] = *(const short8*)(cb + n * 32 + ((g ^ sw) << 2));
            }
#pragma unroll
            for (int s = 0; s < 8; ++s)
                acc[s] = __builtin_amdgcn_mfma_f32_16x16x32_bf16(
                    afrag[ch * 2 + kk], bfr[s], acc[s], 0, 0, 0);
        }
        __syncthreads();
    }

    // --- epilogue: scale by invZ * 1/sqrt(768), store. D: col=mm, row=q*4+reg
    const float invsqrtk = 0.036084391824351615f;
#pragma unroll
    for (int reg = 0; reg < 4; ++reg) {
        int row = q * 4 + reg;
        int rr = rt * 64 + wv * 16 + row;
        if (rr < 196) {
            float scale = sinvz[wv * 16 + row] * invsqrtk;
            float* op = out + (size_t)(b * 196 + rr) * 768 + nb + mm;
#pragma unroll
            for (int s = 0; s < 8; ++s)
                op[s * 16] = acc[s][reg] * scale;
        }
    }
}

extern "C" void kernel_launch(void* const* d_in, const int* in_sizes, int n_in,
                              void* d_out, int out_size, void* d_ws, size_t ws_size,
                              hipStream_t stream) {
    const float* image_emb = (const float*)d_in[0];
    const float* seq_emb   = (const float*)d_in[1];
    const int*   mask      = (const int*)d_in[2];
    const float* image_W   = (const float*)d_in[3];
    const float* image_b   = (const float*)d_in[4];
    const float* seq_W     = (const float*)d_in[5];
    const float* seq_b     = (const float*)d_in[6];
    const float* V         = (const float*)d_in[7];
    float* out = (float*)d_out;

    float* p_ws  = (float*)d_ws;                            // 12544 f (<64 KB)
    float* q_ws  = (float*)((char*)d_ws + (64 << 10));      // 32768 f (128 KB)
    float* wm_ws = (float*)((char*)d_ws + (192 << 10));     // 32768 f (128 KB)

    krows_p<<<dim3(3136), dim3(256), 0, stream>>>(image_emb, image_W, image_b, p_ws);
    krows_q<<<dim3(8192), dim3(256), 0, stream>>>(seq_emb, seq_W, seq_b, q_ws);
    kw<<<dim3(256), dim3(256), 0, stream>>>(q_ws, V, mask, wm_ws);
    kattn<<<dim3(1536), dim3(256), 0, stream>>>(seq_emb, p_ws, wm_ws, out);
}

// Round 2
// 242.645 us; speedup vs baseline: 1.0616x; 1.0616x over previous
//
#include <hip/hip_runtime.h>
#include <cstdint>
#include <cstddef>

// Problem: B=64, R=196, L=512, K=768.
// Algebra: emb = p @ q^T + q^T = (1+p) outer q ==>
//   score[b,r,j] = (1+p[b,r]) * w[b,j],  w[b,:] = q[b,:] @ V
// out[b,r,:] = (1/Z_r) * sum_j exp(c_r*wm_j - M_r) * seq_emb[b,j,:] / sqrt(768)
//
// Round-2 structure:
//   krows_p : p = tanh(image_emb @ image_W)
//   ktrans  : seq fp32 -> seqT[b,k,j] bf16 (transposed, j-contiguous) + fused q=tanh(seq@seq_W)
//   kw      : wm[b,j] = mask ? q_b @ V[:,j] : -1e30
//   kattn2  : alpha-hat (registers, bf16) x seqT-tile (LDS, global_16B->LDS_16B copy) via MFMA
//             with XCD-locality swizzle so the 4 rt-siblings of (b,nt) share an L2.

typedef __attribute__((ext_vector_type(8))) short short8;
typedef __attribute__((ext_vector_type(4))) float f32x4;

__device__ __forceinline__ unsigned short f32_to_bf16(float x) {
    unsigned int u = __float_as_uint(x);
    unsigned int r = (u + 0x7FFFu + ((u >> 16) & 1u)) >> 16;  // RNE
    return (unsigned short)r;
}
__device__ __forceinline__ float bf16_to_f32(unsigned short h) {
    return __uint_as_float(((unsigned int)h) << 16);
}

// ---------------- kernel 1: p[row] = tanh(image_emb[row,:512] . image_W) ----
__global__ __launch_bounds__(256) void krows_p(const float* __restrict__ x,
                                               const float* __restrict__ w,
                                               const float* __restrict__ bias,
                                               float* __restrict__ outp) {
    int wv = threadIdx.x >> 6, lane = threadIdx.x & 63;
    int row = blockIdx.x * 4 + wv;                    // 12544 rows
    const float4* x4 = (const float4*)(x + (size_t)row * 512);
    const float4* w4 = (const float4*)w;
    float s = 0.f;
#pragma unroll
    for (int i = 0; i < 2; ++i) {
        float4 a = x4[i * 64 + lane];
        float4 c = w4[i * 64 + lane];
        s += a.x * c.x + a.y * c.y + a.z * c.z + a.w * c.w;
    }
#pragma unroll
    for (int o = 32; o; o >>= 1) s += __shfl_xor(s, o, 64);
    if (lane == 0) outp[row] = tanhf(s + bias[0]);
}

// ---------------- fallback kernel: q[row] = tanh(seq_emb[row,:768] . seq_W) -
__global__ __launch_bounds__(256) void krows_q(const float* __restrict__ x,
                                               const float* __restrict__ w,
                                               const float* __restrict__ bias,
                                               float* __restrict__ outp) {
    int wv = threadIdx.x >> 6, lane = threadIdx.x & 63;
    int row = blockIdx.x * 4 + wv;                    // 32768 rows
    const float4* x4 = (const float4*)(x + (size_t)row * 768);
    const float4* w4 = (const float4*)w;
    float s = 0.f;
#pragma unroll
    for (int i = 0; i < 3; ++i) {
        float4 a = x4[i * 64 + lane];
        float4 c = w4[i * 64 + lane];
        s += a.x * c.x + a.y * c.y + a.z * c.z + a.w * c.w;
    }
#pragma unroll
    for (int o = 32; o; o >>= 1) s += __shfl_xor(s, o, 64);
    if (lane == 0) outp[row] = tanhf(s + bias[0]);
}

// -------- kernel 2: seqT[b,k,j] = bf16(seq[b,j,k]); q[b,j] = tanh(row.seq_W) -
// grid = 64 b x 8 jt (64 j-rows each), 256 threads. Loops 6 chunks of k=128.
__global__ __launch_bounds__(256) void ktrans(const float* __restrict__ seq,
                                              const float* __restrict__ seqW,
                                              const float* __restrict__ bias,
                                              unsigned short* __restrict__ seqT,
                                              float* __restrict__ qv) {
    __shared__ __align__(16) float sW[768];
    __shared__ __align__(16) unsigned short sT[128 * 74];  // [k=128][j=64], stride 74 (37 u32)
    int b = blockIdx.x >> 3, jt = blockIdx.x & 7;
    int j0 = jt * 64;
    int t = threadIdx.x;
    sW[t] = seqW[t]; sW[t + 256] = seqW[t + 256]; sW[t + 512] = seqW[t + 512];
    int rowin = t >> 5, seg = t & 31;
    const float* base = seq + (size_t)b * 512 * 768 + (size_t)j0 * 768;
    unsigned short* dstb0 = seqT + (size_t)b * 768 * 512 + j0;
    int kr8 = t >> 3, jseg = t & 7;
    float qp[8] = {0.f, 0.f, 0.f, 0.f, 0.f, 0.f, 0.f, 0.f};
    __syncthreads();
    for (int ck = 0; ck < 6; ++ck) {
        if (ck) __syncthreads();                      // sT write-after-read
#pragma unroll
        for (int p = 0; p < 8; ++p) {
            int jl = p * 8 + rowin;
            float4 a = *(const float4*)(base + (size_t)jl * 768 + ck * 128 + seg * 4);
            float4 w = *(const float4*)(sW + ck * 128 + seg * 4);
            qp[p] += a.x * w.x + a.y * w.y + a.z * w.z + a.w * w.w;
            int c0 = seg * 4;
            sT[(c0 + 0) * 74 + jl] = f32_to_bf16(a.x);
            sT[(c0 + 1) * 74 + jl] = f32_to_bf16(a.y);
            sT[(c0 + 2) * 74 + jl] = f32_to_bf16(a.z);
            sT[(c0 + 3) * 74 + jl] = f32_to_bf16(a.w);
        }
        __syncthreads();
        const unsigned int* sT32 = (const unsigned int*)sT;
        unsigned short* dstb = dstb0 + (size_t)ck * 128 * 512;
#pragma unroll
        for (int wp = 0; wp < 4; ++wp) {
            int kr = wp * 32 + kr8;
            uint4 v;
            v.x = sT32[kr * 37 + jseg * 4 + 0];
            v.y = sT32[kr * 37 + jseg * 4 + 1];
            v.z = sT32[kr * 37 + jseg * 4 + 2];
            v.w = sT32[kr * 37 + jseg * 4 + 3];
            *(uint4*)(dstb + (size_t)kr * 512 + jseg * 8) = v;
        }
    }
    // q reduction: qp[p] holds row (p*8+rowin)'s partial over this thread's 24 cols;
    // the 32 threads sharing rowin are a contiguous 32-lane half-wave.
#pragma unroll
    for (int p = 0; p < 8; ++p) {
        float s = qp[p];
#pragma unroll
        for (int o = 16; o; o >>= 1) s += __shfl_xor(s, o, 64);
        if ((t & 31) == 0) qv[b * 512 + j0 + p * 8 + rowin] = tanhf(s + bias[0]);
    }
}

// ------- kernel 3: wm[b,j] = mask[b,j] ? (q[b,:] @ V[:,j]) : -1e30 ----------
__global__ __launch_bounds__(256) void kw(const float* __restrict__ qv,
                                          const float* __restrict__ V,
                                          const int* __restrict__ mask,
                                          float* __restrict__ wm) {
    __shared__ __align__(16) float sq[512];
    __shared__ __align__(16) float sacc[8][32][4];
    int b = blockIdx.x >> 2, jc = blockIdx.x & 3;
    int t = threadIdx.x;
    sq[t] = qv[b * 512 + t];
    sq[t + 256] = qv[b * 512 + t + 256];
    __syncthreads();
    int jt = t & 31, lg = t >> 5;
    const float4* V4 = (const float4*)V;
    int col4 = jc * 32 + jt;
    float ax = 0.f, ay = 0.f, az = 0.f, aw = 0.f;
    int lbase = lg * 64;
#pragma unroll 8
    for (int li = 0; li < 64; ++li) {
        int l = lbase + li;
        float qq = sq[l];
        float4 v = V4[(size_t)l * 128 + col4];
        ax += qq * v.x; ay += qq * v.y; az += qq * v.z; aw += qq * v.w;
    }
    sacc[lg][jt][0] = ax; sacc[lg][jt][1] = ay;
    sacc[lg][jt][2] = az; sacc[lg][jt][3] = aw;
    __syncthreads();
    if (t < 32) {
        float sx = 0.f, sy = 0.f, sz = 0.f, sw = 0.f;
#pragma unroll
        for (int g = 0; g < 8; ++g) {
            sx += sacc[g][t][0]; sy += sacc[g][t][1];
            sz += sacc[g][t][2]; sw += sacc[g][t][3];
        }
        const int* mrow = mask + b * 512 + jc * 128 + t * 4;
        float4 o;
        o.x = mrow[0] ? sx : -1e30f;
        o.y = mrow[1] ? sy : -1e30f;
        o.z = mrow[2] ? sz : -1e30f;
        o.w = mrow[3] ? sw : -1e30f;
        ((float4*)(wm + b * 512 + jc * 128))[t] = o;
    }
}

// ------- kernel 4 v2: softmax-weights (regs) x seqT bf16 tile (LDS) ---------
// grid raw 0..1535 swizzled: g=(b,nt) group -> XCD g%8 (round-robin assumption),
// rt-siblings 8 apart so they co-schedule on one XCD and share its L2.
__global__ __launch_bounds__(256, 2) void kattn2(const unsigned short* __restrict__ seqT,
                                                 const float* __restrict__ p,
                                                 const float* __restrict__ wm,
                                                 float* __restrict__ out) {
    __shared__ __align__(16) unsigned short sB[2][128 * 64];  // 2 x 16 KB
    __shared__ __align__(16) float swm[512];
    __shared__ float sinvz[64];
    __shared__ float sred[16];

    int raw = blockIdx.x;
    int g  = ((raw >> 5) << 3) + (raw & 7);           // 0..383 = (b,nt)
    int rt = (raw >> 3) & 3;
    int b  = g / 6, nt = g - b * 6;
    int t  = threadIdx.x;
    int wv = t >> 6, lane = t & 63;
    int mm = lane & 15, q = lane >> 4;
    int nb = nt * 128;

    // --- phase 0a: wm -> LDS, block max/min over unmasked ---
    float v0 = wm[b * 512 + t];
    float v1 = wm[b * 512 + t + 256];
    swm[t] = v0; swm[t + 256] = v1;
    float lmax = fmaxf(v0, v1);
    float fa = (v0 > -1e29f) ? v0 : 1e30f;
    float fb = (v1 > -1e29f) ? v1 : 1e30f;
    float lmin = fminf(fa, fb);
#pragma unroll
    for (int o = 32; o; o >>= 1) {
        lmax = fmaxf(lmax, __shfl_xor(lmax, o, 64));
        lmin = fminf(lmin, __shfl_xor(lmin, o, 64));
    }
    if (lane == 0) { sred[wv] = lmax; sred[8 + wv] = lmin; }
    __syncthreads();
    float wmax = fmaxf(fmaxf(sred[0], sred[1]), fmaxf(sred[2], sred[3]));
    float wmin = fminf(fminf(sred[8], sred[9]), fminf(sred[10], sred[11]));

    // --- per-row softmax params ---
    int rl = wv * 16 + mm;
    int r  = rt * 64 + rl;
    bool valid = r < 196;
    int pidx = b * 196 + (valid ? r : 195);
    float c = 1.0f + p[pidx];
    float M = (c >= 0.f) ? c * wmax : c * wmin;

    // --- phase 0b: alpha-hat A-fragments in registers + Z ---
    short8 afrag[16];
    float zsum = 0.f;
    const f32x4* swm4 = (const f32x4*)swm;
#pragma unroll
    for (int tk = 0; tk < 16; ++tk) {
        int jb = tk * 32 + q * 8;
        f32x4 w0 = swm4[jb >> 2];
        f32x4 w1 = swm4[(jb >> 2) + 1];
        short8 af;
#pragma unroll
        for (int jj = 0; jj < 8; ++jj) {
            float ww = (jj < 4) ? w0[jj] : w1[jj - 4];
            float e = valid ? __expf(c * ww - M) : 0.f;
            unsigned short h = f32_to_bf16(e);
            zsum += bf16_to_f32(h);
            af[jj] = (short)h;
        }
        afrag[tk] = af;
    }
    zsum += __shfl_xor(zsum, 16, 64);
    zsum += __shfl_xor(zsum, 32, 64);
    if (q == 0) sinvz[rl] = 1.0f / zsum;

    f32x4 acc[8];
#pragma unroll
    for (int s = 0; s < 8; ++s) acc[s] = (f32x4){0.f, 0.f, 0.f, 0.f};

    // --- staging: pure 16B copy seqT -> swizzled LDS [n][jg^sw] ---
    const unsigned short* seqTb = seqT + (size_t)b * 768 * 512 + (size_t)nb * 512;
    int nrow = t >> 3, jg = t & 7;
    auto stage = [&](int ch, int buf) {
        unsigned short* sb = sB[buf];
#pragma unroll
        for (int pp = 0; pp < 4; ++pp) {
            int n = pp * 32 + nrow;
            short8 v = *(const short8*)(seqTb + (size_t)n * 512 + ch * 64 + jg * 8);
            int sw = (n ^ (n >> 3)) & 7;
            *(short8*)(sb + n * 64 + ((jg ^ sw) << 3)) = v;
        }
    };

    __syncthreads();
    stage(0, 0);
    __syncthreads();
#pragma unroll
    for (int ch = 0; ch < 8; ++ch) {
        if (ch < 7) stage(ch + 1, (ch + 1) & 1);
        const unsigned short* cb = sB[ch & 1];
#pragma unroll
        for (int kk = 0; kk < 2; ++kk) {
            short8 bfr[8];
#pragma unroll
            for (int s = 0; s < 8; ++s) {
                int n = s * 16 + mm;
                int sw = (n ^ (n >> 3)) & 7;
                bfr[s] = *(const short8*)(cb + n * 64 + ((((kk << 2) + q) ^ sw) << 3));
            }
#pragma unroll
            for (int s = 0; s < 8; ++s)
                acc[s] = __builtin_amdgcn_mfma_f32_16x16x32_bf16(
                    afrag[(ch << 1) + kk], bfr[s], acc[s], 0, 0, 0);
        }
        __syncthreads();
    }

    // --- epilogue: D layout col=mm, row=q*4+reg ---
    const float invsqrtk = 0.036084391824351615f;
#pragma unroll
    for (int reg = 0; reg < 4; ++reg) {
        int row = q * 4 + reg;
        int rr = rt * 64 + wv * 16 + row;
        if (rr < 196) {
            float scale = sinvz[wv * 16 + row] * invsqrtk;
            float* op = out + (size_t)(b * 196 + rr) * 768 + nb + mm;
#pragma unroll
            for (int s = 0; s < 8; ++s)
                op[s * 16] = acc[s][reg] * scale;
        }
    }
}

// ------- fallback kernel 4 (round-1, fp32-source staging) -------------------
__global__ __launch_bounds__(256, 2) void kattn(const float* __restrict__ seq,
                                                const float* __restrict__ p,
                                                const float* __restrict__ wm,
                                                float* __restrict__ out) {
    __shared__ __align__(16) unsigned int sseq[2][128 * 32];
    __shared__ __align__(16) float swm[512];
    __shared__ float sinvz[64];
    __shared__ float sred[16];

    int id = blockIdx.x;
    int rt = id & 3;
    int nt = (id >> 2) % 6;
    int b  = id / 24;
    int t  = threadIdx.x;
    int wv = t >> 6, lane = t & 63;
    int mm = lane & 15, q = lane >> 4;
    int nb = nt * 128;

    float v0 = wm[b * 512 + t];
    float v1 = wm[b * 512 + t + 256];
    swm[t] = v0; swm[t + 256] = v1;
    float lmax = fmaxf(v0, v1);
    float fa = (v0 > -1e29f) ? v0 : 1e30f;
    float fb = (v1 > -1e29f) ? v1 : 1e30f;
    float lmin = fminf(fa, fb);
#pragma unroll
    for (int o = 32; o; o >>= 1) {
        lmax = fmaxf(lmax, __shfl_xor(lmax, o, 64));
        lmin = fminf(lmin, __shfl_xor(lmin, o, 64));
    }
    if (lane == 0) { sred[wv] = lmax; sred[8 + wv] = lmin; }
    __syncthreads();
    float wmax = fmaxf(fmaxf(sred[0], sred[1]), fmaxf(sred[2], sred[3]));
    float wmin = fminf(fminf(sred[8], sred[9]), fminf(sred[10], sred[11]));

    int rl = wv * 16 + mm;
    int r  = rt * 64 + rl;
    bool valid = r < 196;
    int pidx = b * 196 + (valid ? r : 195);
    float c = 1.0f + p[pidx];
    float M = (c >= 0.f) ? c * wmax : c * wmin;

    short8 afrag[16];
    float zsum = 0.f;
    const f32x4* swm4 = (const f32x4*)swm;
#pragma unroll
    for (int tk = 0; tk < 16; ++tk) {
        int jb = tk * 32 + q * 8;
        f32x4 w0 = swm4[jb >> 2];
        f32x4 w1 = swm4[(jb >> 2) + 1];
        short8 af;
#pragma unroll
        for (int jj = 0; jj < 8; ++jj) {
            float ww = (jj < 4) ? w0[jj] : w1[jj - 4];
            float e = valid ? __expf(c * ww - M) : 0.f;
            unsigned short h = f32_to_bf16(e);
            zsum += bf16_to_f32(h);
            af[jj] = (short)h;
        }
        afrag[tk] = af;
    }
    zsum += __shfl_xor(zsum, 16, 64);
    zsum += __shfl_xor(zsum, 32, 64);
    if (q == 0) sinvz[rl] = 1.0f / zsum;

    f32x4 acc[8];
#pragma unroll
    for (int s = 0; s < 8; ++s) acc[s] = (f32x4){0.f, 0.f, 0.f, 0.f};

    const float* seqb = seq + (size_t)b * 512 * 768 + nb;
    int tl = t & 31, jp = t >> 5;
    int n0 = tl * 4;
    auto stage = [&](int ch, int buf) {
        unsigned int* sb = sseq[buf];
#pragma unroll
        for (int pass = 0; pass < 4; ++pass) {
            int jl = pass * 16 + jp * 2;
            int jglob = ch * 64 + jl;
            float4 a0 = *(const float4*)(seqb + (size_t)jglob * 768 + n0);
            float4 a1 = *(const float4*)(seqb + (size_t)(jglob + 1) * 768 + n0);
            float a0v[4] = {a0.x, a0.y, a0.z, a0.w};
            float a1v[4] = {a1.x, a1.y, a1.z, a1.w};
            int g = jl >> 3;
            int wo = (jl & 7) >> 1;
#pragma unroll
            for (int i = 0; i < 4; ++i) {
                int n = n0 + i;
                int sw = (n ^ (n >> 3)) & 7;
                unsigned int pk = (unsigned int)f32_to_bf16(a0v[i]) |
                                  ((unsigned int)f32_to_bf16(a1v[i]) << 16);
                sb[n * 32 + ((g ^ sw) << 2) + wo] = pk;
            }
        }
    };

    __syncthreads();
    stage(0, 0);
    __syncthreads();
#pragma unroll
    for (int ch = 0; ch < 8; ++ch) {
        if (ch < 7) stage(ch + 1, (ch + 1) & 1);
        const unsigned int* cb = sseq[ch & 1];
#pragma unroll
        for (int kk = 0; kk < 2; ++kk) {
            short8 bfr[8];
#pragma unroll
            for (int s = 0; s < 8; ++s) {
                int n = s * 16 + mm;
                int g = kk * 4 + q;
                int sw = (n ^ (n >> 3)) & 7;
                bfr[s] = *(const short8*)(cb + n * 32 + ((g ^ sw) << 2));
            }
#pragma unroll
            for (int s = 0; s < 8; ++s)
                acc[s] = __builtin_amdgcn_mfma_f32_16x16x32_bf16(
                    afrag[ch * 2 + kk], bfr[s], acc[s], 0, 0, 0);
        }
        __syncthreads();
    }

    const float invsqrtk = 0.036084391824351615f;
#pragma unroll
    for (int reg = 0; reg < 4; ++reg) {
        int row = q * 4 + reg;
        int rr = rt * 64 + wv * 16 + row;
        if (rr < 196) {
            float scale = sinvz[wv * 16 + row] * invsqrtk;
            float* op = out + (size_t)(b * 196 + rr) * 768 + nb + mm;
#pragma unroll
            for (int s = 0; s < 8; ++s)
                op[s * 16] = acc[s][reg] * scale;
        }
    }
}

extern "C" void kernel_launch(void* const* d_in, const int* in_sizes, int n_in,
                              void* d_out, int out_size, void* d_ws, size_t ws_size,
                              hipStream_t stream) {
    const float* image_emb = (const float*)d_in[0];
    const float* seq_emb   = (const float*)d_in[1];
    const int*   mask      = (const int*)d_in[2];
    const float* image_W   = (const float*)d_in[3];
    const float* image_b   = (const float*)d_in[4];
    const float* seq_W     = (const float*)d_in[5];
    const float* seq_b     = (const float*)d_in[6];
    const float* V         = (const float*)d_in[7];
    float* out = (float*)d_out;

    float* p_ws  = (float*)d_ws;                             // 12544 f
    float* q_ws  = (float*)((char*)d_ws + (64 << 10));       // 32768 f
    float* wm_ws = (float*)((char*)d_ws + (192 << 10));      // 32768 f
    unsigned short* seqT = (unsigned short*)((char*)d_ws + (384 << 10));  // 64*768*512 bf16

    size_t need = (size_t)(384 << 10) + (size_t)64 * 768 * 512 * 2;
    krows_p<<<dim3(3136), dim3(256), 0, stream>>>(image_emb, image_W, image_b, p_ws);
    if (ws_size >= need) {
        ktrans<<<dim3(512), dim3(256), 0, stream>>>(seq_emb, seq_W, seq_b, seqT, q_ws);
        kw<<<dim3(256), dim3(256), 0, stream>>>(q_ws, V, mask, wm_ws);
        kattn2<<<dim3(1536), dim3(256), 0, stream>>>(seqT, p_ws, wm_ws, out);
    } else {
        krows_q<<<dim3(8192), dim3(256), 0, stream>>>(seq_emb, seq_W, seq_b, q_ws);
        kw<<<dim3(256), dim3(256), 0, stream>>>(q_ws, V, mask, wm_ws);
        kattn<<<dim3(1536), dim3(256), 0, stream>>>(seq_emb, p_ws, wm_ws, out);
    }
}

// Round 3
// 239.088 us; speedup vs baseline: 1.0774x; 1.0149x over previous
//
#include <hip/hip_runtime.h>
#include <cstdint>
#include <cstddef>

// Problem: B=64, R=196, L=512, K=768.
// Algebra: emb = p @ q^T + q^T = (1+p) outer q ==>
//   score[b,r,j] = (1+p[b,r]) * w[b,j],  w[b,:] = q[b,:] @ V
// out[b,r,:] = (1/Z_r) * sum_j exp(c_r*wm_j - M_r) * seq_emb[b,j,:] / sqrt(768)
//
// Round-3 structure:
//   kprep  : [blocks 0..511]   seq fp32 -> seqT[b,k,j] bf16 (packed cvt, b64 LDS
//                              writes, b64 reads -> 16B stores) + fused q=tanh(seq@W)
//            [blocks 512..3647] p = tanh(image_emb @ image_W)
//   kw     : wm[b,j] = mask ? q_b @ V[:,j] : -1e30
//   kattn2 : alpha-hat (regs, bf16) x seqT tile (LDS, 16B copy) via MFMA,
//            XCD-locality swizzle so rt-siblings share an L2.

typedef __attribute__((ext_vector_type(8))) short short8;
typedef __attribute__((ext_vector_type(4))) float f32x4;

__device__ __forceinline__ unsigned short f32_to_bf16(float x) {
    unsigned int u = __float_as_uint(x);
    unsigned int r = (u + 0x7FFFu + ((u >> 16) & 1u)) >> 16;  // RNE
    return (unsigned short)r;
}
__device__ __forceinline__ float bf16_to_f32(unsigned short h) {
    return __uint_as_float(((unsigned int)h) << 16);
}

#if defined(__has_builtin)
#if __has_builtin(__builtin_amdgcn_cvt_pk_bf16_f32)
#define HAVE_PK_BF16 1
#endif
#endif

__device__ __forceinline__ unsigned int pk_bf16(float a, float b) {
#ifdef HAVE_PK_BF16
    typedef __attribute__((ext_vector_type(2))) __bf16 bf16x2;
    bf16x2 v = __builtin_amdgcn_cvt_pk_bf16_f32(a, b);
    return __builtin_bit_cast(unsigned int, v);
#else
    return (unsigned int)f32_to_bf16(a) | ((unsigned int)f32_to_bf16(b) << 16);
#endif
}

// ---- kernel 1: fused transpose+q (blocks 0..511) and p (blocks 512..3647) --
__global__ __launch_bounds__(256) void kprep(const float* __restrict__ seq,
                                             const float* __restrict__ seqW,
                                             const float* __restrict__ seqBias,
                                             const float* __restrict__ img,
                                             const float* __restrict__ imgW,
                                             const float* __restrict__ imgBias,
                                             unsigned short* __restrict__ seqT,
                                             float* __restrict__ qv,
                                             float* __restrict__ pv) {
    __shared__ __align__(16) unsigned int sT[128 * 32];   // [k][16 j-quads x 2 u32]
    __shared__ __align__(16) float sW[768];

    if (blockIdx.x >= 512) {
        // ---- krows_p: p[row] = tanh(image_emb[row,:512] . image_W) ----
        int wv = threadIdx.x >> 6, lane = threadIdx.x & 63;
        int row = (blockIdx.x - 512) * 4 + wv;            // 12544 rows
        const float4* x4 = (const float4*)(img + (size_t)row * 512);
        const float4* w4 = (const float4*)imgW;
        float s = 0.f;
#pragma unroll
        for (int i = 0; i < 2; ++i) {
            float4 a = x4[i * 64 + lane];
            float4 c = w4[i * 64 + lane];
            s += a.x * c.x + a.y * c.y + a.z * c.z + a.w * c.w;
        }
#pragma unroll
        for (int o = 32; o; o >>= 1) s += __shfl_xor(s, o, 64);
        if (lane == 0) pv[row] = tanhf(s + imgBias[0]);
        return;
    }

    // ---- ktrans v2: 64 j-rows x 768 k, 6 chunks of 128 ----
    int b = blockIdx.x >> 3, jt = blockIdx.x & 7;
    int j0 = jt * 64;
    int t = threadIdx.x;
    sW[t] = seqW[t]; sW[t + 256] = seqW[t + 256]; sW[t + 512] = seqW[t + 512];

    int quad = t >> 4, kseg = t & 15;                     // write map: 4 j-rows x 4k
    int qk = quad ^ kseg;                                 // swizzle base
    const float* base = seq + (size_t)b * 512 * 768 + (size_t)(j0 + quad * 4) * 768;
    int jg = t & 7, krow = t >> 3;                        // read map: 8 j x b128
    unsigned short* dst0 = seqT + (size_t)b * 768 * 512 + j0;
    float qp[4] = {0.f, 0.f, 0.f, 0.f};
    __syncthreads();

    for (int ck = 0; ck < 6; ++ck) {
        if (ck) __syncthreads();                          // sT WAR
#pragma unroll
        for (int rp = 0; rp < 2; ++rp) {
            int kq = rp * 64 + kseg * 4;                  // 0..124
            int kg = ck * 128 + kq;
            float4 r0 = *(const float4*)(base + 0 * 768 + kg);
            float4 r1 = *(const float4*)(base + 1 * 768 + kg);
            float4 r2 = *(const float4*)(base + 2 * 768 + kg);
            float4 r3 = *(const float4*)(base + 3 * 768 + kg);
            float4 w  = *(const float4*)(sW + kg);
            qp[0] += r0.x * w.x + r0.y * w.y + r0.z * w.z + r0.w * w.w;
            qp[1] += r1.x * w.x + r1.y * w.y + r1.z * w.z + r1.w * w.w;
            qp[2] += r2.x * w.x + r2.y * w.y + r2.z * w.z + r2.w * w.w;
            qp[3] += r3.x * w.x + r3.y * w.y + r3.z * w.z + r3.w * w.w;
            float a0[4] = {r0.x, r0.y, r0.z, r0.w};
            float a1[4] = {r1.x, r1.y, r1.z, r1.w};
            float a2[4] = {r2.x, r2.y, r2.z, r2.w};
            float a3[4] = {r3.x, r3.y, r3.z, r3.w};
#pragma unroll
            for (int i = 0; i < 4; ++i) {
                int k = kq + i;
                int col = (qk ^ (i << 2)) & 15;           // = quad ^ s(k)
                uint2 v;
                v.x = pk_bf16(a0[i], a1[i]);
                v.y = pk_bf16(a2[i], a3[i]);
                *(uint2*)(sT + k * 32 + col * 2) = v;
            }
        }
        __syncthreads();
        unsigned short* dst = dst0 + (size_t)ck * 128 * 512;
#pragma unroll
        for (int wp = 0; wp < 4; ++wp) {
            int k = wp * 32 + krow;
            int s = ((k >> 2) & 15) ^ ((k & 3) << 2);
            int c0 = ((jg << 1) ^ s) & 15;
            int c1 = ((jg << 1) ^ 1 ^ s) & 15;
            uint2 va = *(const uint2*)(sT + k * 32 + c0 * 2);
            uint2 vb = *(const uint2*)(sT + k * 32 + c1 * 2);
            uint4 o;
            o.x = va.x; o.y = va.y; o.z = vb.x; o.w = vb.y;
            *(uint4*)(dst + (size_t)k * 512 + jg * 8) = o;
        }
    }
    // q reduction over kseg (16-lane groups within a wave)
#pragma unroll
    for (int rr = 0; rr < 4; ++rr) {
        float s = qp[rr];
        s += __shfl_xor(s, 8, 64);
        s += __shfl_xor(s, 4, 64);
        s += __shfl_xor(s, 2, 64);
        s += __shfl_xor(s, 1, 64);
        if (kseg == 0) qv[b * 512 + j0 + quad * 4 + rr] = tanhf(s + seqBias[0]);
    }
}

// ---------------- fallback: p rows standalone -------------------------------
__global__ __launch_bounds__(256) void krows_p(const float* __restrict__ x,
                                               const float* __restrict__ w,
                                               const float* __restrict__ bias,
                                               float* __restrict__ outp) {
    int wv = threadIdx.x >> 6, lane = threadIdx.x & 63;
    int row = blockIdx.x * 4 + wv;
    const float4* x4 = (const float4*)(x + (size_t)row * 512);
    const float4* w4 = (const float4*)w;
    float s = 0.f;
#pragma unroll
    for (int i = 0; i < 2; ++i) {
        float4 a = x4[i * 64 + lane];
        float4 c = w4[i * 64 + lane];
        s += a.x * c.x + a.y * c.y + a.z * c.z + a.w * c.w;
    }
#pragma unroll
    for (int o = 32; o; o >>= 1) s += __shfl_xor(s, o, 64);
    if (lane == 0) outp[row] = tanhf(s + bias[0]);
}

// ---------------- fallback: q rows standalone -------------------------------
__global__ __launch_bounds__(256) void krows_q(const float* __restrict__ x,
                                               const float* __restrict__ w,
                                               const float* __restrict__ bias,
                                               float* __restrict__ outp) {
    int wv = threadIdx.x >> 6, lane = threadIdx.x & 63;
    int row = blockIdx.x * 4 + wv;
    const float4* x4 = (const float4*)(x + (size_t)row * 768);
    const float4* w4 = (const float4*)w;
    float s = 0.f;
#pragma unroll
    for (int i = 0; i < 3; ++i) {
        float4 a = x4[i * 64 + lane];
        float4 c = w4[i * 64 + lane];
        s += a.x * c.x + a.y * c.y + a.z * c.z + a.w * c.w;
    }
#pragma unroll
    for (int o = 32; o; o >>= 1) s += __shfl_xor(s, o, 64);
    if (lane == 0) outp[row] = tanhf(s + bias[0]);
}

// ------- kernel 3: wm[b,j] = mask[b,j] ? (q[b,:] @ V[:,j]) : -1e30 ----------
__global__ __launch_bounds__(256) void kw(const float* __restrict__ qv,
                                          const float* __restrict__ V,
                                          const int* __restrict__ mask,
                                          float* __restrict__ wm) {
    __shared__ __align__(16) float sq[512];
    __shared__ __align__(16) float sacc[8][32][4];
    int b = blockIdx.x >> 2, jc = blockIdx.x & 3;
    int t = threadIdx.x;
    sq[t] = qv[b * 512 + t];
    sq[t + 256] = qv[b * 512 + t + 256];
    __syncthreads();
    int jt = t & 31, lg = t >> 5;
    const float4* V4 = (const float4*)V;
    int col4 = jc * 32 + jt;
    float ax = 0.f, ay = 0.f, az = 0.f, aw = 0.f;
    int lbase = lg * 64;
#pragma unroll 8
    for (int li = 0; li < 64; ++li) {
        int l = lbase + li;
        float qq = sq[l];
        float4 v = V4[(size_t)l * 128 + col4];
        ax += qq * v.x; ay += qq * v.y; az += qq * v.z; aw += qq * v.w;
    }
    sacc[lg][jt][0] = ax; sacc[lg][jt][1] = ay;
    sacc[lg][jt][2] = az; sacc[lg][jt][3] = aw;
    __syncthreads();
    if (t < 32) {
        float sx = 0.f, sy = 0.f, sz = 0.f, sw = 0.f;
#pragma unroll
        for (int g = 0; g < 8; ++g) {
            sx += sacc[g][t][0]; sy += sacc[g][t][1];
            sz += sacc[g][t][2]; sw += sacc[g][t][3];
        }
        const int* mrow = mask + b * 512 + jc * 128 + t * 4;
        float4 o;
        o.x = mrow[0] ? sx : -1e30f;
        o.y = mrow[1] ? sy : -1e30f;
        o.z = mrow[2] ? sz : -1e30f;
        o.w = mrow[3] ? sw : -1e30f;
        ((float4*)(wm + b * 512 + jc * 128))[t] = o;
    }
}

// ------- kernel 4: softmax-weights (regs) x seqT bf16 tile (LDS) ------------
__global__ __launch_bounds__(256, 2) void kattn2(const unsigned short* __restrict__ seqT,
                                                 const float* __restrict__ p,
                                                 const float* __restrict__ wm,
                                                 float* __restrict__ out) {
    __shared__ __align__(16) unsigned short sB[2][128 * 64];  // 2 x 16 KB
    __shared__ __align__(16) float swm[512];
    __shared__ float sinvz[64];
    __shared__ float sred[16];

    int raw = blockIdx.x;
    int g  = ((raw >> 5) << 3) + (raw & 7);           // 0..383 = (b,nt)
    int rt = (raw >> 3) & 3;
    int b  = g / 6, nt = g - b * 6;
    int t  = threadIdx.x;
    int wv = t >> 6, lane = t & 63;
    int mm = lane & 15, q = lane >> 4;
    int nb = nt * 128;

    float v0 = wm[b * 512 + t];
    float v1 = wm[b * 512 + t + 256];
    swm[t] = v0; swm[t + 256] = v1;
    float lmax = fmaxf(v0, v1);
    float fa = (v0 > -1e29f) ? v0 : 1e30f;
    float fb = (v1 > -1e29f) ? v1 : 1e30f;
    float lmin = fminf(fa, fb);
#pragma unroll
    for (int o = 32; o; o >>= 1) {
        lmax = fmaxf(lmax, __shfl_xor(lmax, o, 64));
        lmin = fminf(lmin, __shfl_xor(lmin, o, 64));
    }
    if (lane == 0) { sred[wv] = lmax; sred[8 + wv] = lmin; }
    __syncthreads();
    float wmax = fmaxf(fmaxf(sred[0], sred[1]), fmaxf(sred[2], sred[3]));
    float wmin = fminf(fminf(sred[8], sred[9]), fminf(sred[10], sred[11]));

    int rl = wv * 16 + mm;
    int r  = rt * 64 + rl;
    bool valid = r < 196;
    int pidx = b * 196 + (valid ? r : 195);
    float c = 1.0f + p[pidx];
    float M = (c >= 0.f) ? c * wmax : c * wmin;

    short8 afrag[16];
    float zsum = 0.f;
    const f32x4* swm4 = (const f32x4*)swm;
#pragma unroll
    for (int tk = 0; tk < 16; ++tk) {
        int jb = tk * 32 + q * 8;
        f32x4 w0 = swm4[jb >> 2];
        f32x4 w1 = swm4[(jb >> 2) + 1];
        short8 af;
#pragma unroll
        for (int jj = 0; jj < 8; ++jj) {
            float ww = (jj < 4) ? w0[jj] : w1[jj - 4];
            float e = valid ? __expf(c * ww - M) : 0.f;
            unsigned short h = f32_to_bf16(e);
            zsum += bf16_to_f32(h);
            af[jj] = (short)h;
        }
        afrag[tk] = af;
    }
    zsum += __shfl_xor(zsum, 16, 64);
    zsum += __shfl_xor(zsum, 32, 64);
    if (q == 0) sinvz[rl] = 1.0f / zsum;

    f32x4 acc[8];
#pragma unroll
    for (int s = 0; s < 8; ++s) acc[s] = (f32x4){0.f, 0.f, 0.f, 0.f};

    const unsigned short* seqTb = seqT + (size_t)b * 768 * 512 + (size_t)nb * 512;
    int nrow = t >> 3, jg = t & 7;
    auto stage = [&](int ch, int buf) {
        unsigned short* sb = sB[buf];
#pragma unroll
        for (int pp = 0; pp < 4; ++pp) {
            int n = pp * 32 + nrow;
            short8 v = *(const short8*)(seqTb + (size_t)n * 512 + ch * 64 + jg * 8);
            int sw = (n ^ (n >> 3)) & 7;
            *(short8*)(sb + n * 64 + ((jg ^ sw) << 3)) = v;
        }
    };

    __syncthreads();
    stage(0, 0);
    __syncthreads();
#pragma unroll
    for (int ch = 0; ch < 8; ++ch) {
        if (ch < 7) stage(ch + 1, (ch + 1) & 1);
        const unsigned short* cb = sB[ch & 1];
#pragma unroll
        for (int kk = 0; kk < 2; ++kk) {
            short8 bfr[8];
#pragma unroll
            for (int s = 0; s < 8; ++s) {
                int n = s * 16 + mm;
                int sw = (n ^ (n >> 3)) & 7;
                bfr[s] = *(const short8*)(cb + n * 64 + ((((kk << 2) + q) ^ sw) << 3));
            }
#pragma unroll
            for (int s = 0; s < 8; ++s)
                acc[s] = __builtin_amdgcn_mfma_f32_16x16x32_bf16(
                    afrag[(ch << 1) + kk], bfr[s], acc[s], 0, 0, 0);
        }
        __syncthreads();
    }

    const float invsqrtk = 0.036084391824351615f;
#pragma unroll
    for (int reg = 0; reg < 4; ++reg) {
        int row = q * 4 + reg;
        int rr = rt * 64 + wv * 16 + row;
        if (rr < 196) {
            float scale = sinvz[wv * 16 + row] * invsqrtk;
            float* op = out + (size_t)(b * 196 + rr) * 768 + nb + mm;
#pragma unroll
            for (int s = 0; s < 8; ++s)
                op[s * 16] = acc[s][reg] * scale;
        }
    }
}

// ------- fallback kernel 4 (fp32-source staging, round-1) -------------------
__global__ __launch_bounds__(256, 2) void kattn(const float* __restrict__ seq,
                                                const float* __restrict__ p,
                                                const float* __restrict__ wm,
                                                float* __restrict__ out) {
    __shared__ __align__(16) unsigned int sseq[2][128 * 32];
    __shared__ __align__(16) float swm[512];
    __shared__ float sinvz[64];
    __shared__ float sred[16];

    int id = blockIdx.x;
    int rt = id & 3;
    int nt = (id >> 2) % 6;
    int b  = id / 24;
    int t  = threadIdx.x;
    int wv = t >> 6, lane = t & 63;
    int mm = lane & 15, q = lane >> 4;
    int nb = nt * 128;

    float v0 = wm[b * 512 + t];
    float v1 = wm[b * 512 + t + 256];
    swm[t] = v0; swm[t + 256] = v1;
    float lmax = fmaxf(v0, v1);
    float fa = (v0 > -1e29f) ? v0 : 1e30f;
    float fb = (v1 > -1e29f) ? v1 : 1e30f;
    float lmin = fminf(fa, fb);
#pragma unroll
    for (int o = 32; o; o >>= 1) {
        lmax = fmaxf(lmax, __shfl_xor(lmax, o, 64));
        lmin = fminf(lmin, __shfl_xor(lmin, o, 64));
    }
    if (lane == 0) { sred[wv] = lmax; sred[8 + wv] = lmin; }
    __syncthreads();
    float wmax = fmaxf(fmaxf(sred[0], sred[1]), fmaxf(sred[2], sred[3]));
    float wmin = fminf(fminf(sred[8], sred[9]), fminf(sred[10], sred[11]));

    int rl = wv * 16 + mm;
    int r  = rt * 64 + rl;
    bool valid = r < 196;
    int pidx = b * 196 + (valid ? r : 195);
    float c = 1.0f + p[pidx];
    float M = (c >= 0.f) ? c * wmax : c * wmin;

    short8 afrag[16];
    float zsum = 0.f;
    const f32x4* swm4 = (const f32x4*)swm;
#pragma unroll
    for (int tk = 0; tk < 16; ++tk) {
        int jb = tk * 32 + q * 8;
        f32x4 w0 = swm4[jb >> 2];
        f32x4 w1 = swm4[(jb >> 2) + 1];
        short8 af;
#pragma unroll
        for (int jj = 0; jj < 8; ++jj) {
            float ww = (jj < 4) ? w0[jj] : w1[jj - 4];
            float e = valid ? __expf(c * ww - M) : 0.f;
            unsigned short h = f32_to_bf16(e);
            zsum += bf16_to_f32(h);
            af[jj] = (short)h;
        }
        afrag[tk] = af;
    }
    zsum += __shfl_xor(zsum, 16, 64);
    zsum += __shfl_xor(zsum, 32, 64);
    if (q == 0) sinvz[rl] = 1.0f / zsum;

    f32x4 acc[8];
#pragma unroll
    for (int s = 0; s < 8; ++s) acc[s] = (f32x4){0.f, 0.f, 0.f, 0.f};

    const float* seqb = seq + (size_t)b * 512 * 768 + nb;
    int tl = t & 31, jp = t >> 5;
    int n0 = tl * 4;
    auto stage = [&](int ch, int buf) {
        unsigned int* sb = sseq[buf];
#pragma unroll
        for (int pass = 0; pass < 4; ++pass) {
            int jl = pass * 16 + jp * 2;
            int jglob = ch * 64 + jl;
            float4 a0 = *(const float4*)(seqb + (size_t)jglob * 768 + n0);
            float4 a1 = *(const float4*)(seqb + (size_t)(jglob + 1) * 768 + n0);
            float a0v[4] = {a0.x, a0.y, a0.z, a0.w};
            float a1v[4] = {a1.x, a1.y, a1.z, a1.w};
            int g = jl >> 3;
            int wo = (jl & 7) >> 1;
#pragma unroll
            for (int i = 0; i < 4; ++i) {
                int n = n0 + i;
                int sw = (n ^ (n >> 3)) & 7;
                unsigned int pk = (unsigned int)f32_to_bf16(a0v[i]) |
                                  ((unsigned int)f32_to_bf16(a1v[i]) << 16);
                sb[n * 32 + ((g ^ sw) << 2) + wo] = pk;
            }
        }
    };

    __syncthreads();
    stage(0, 0);
    __syncthreads();
#pragma unroll
    for (int ch = 0; ch < 8; ++ch) {
        if (ch < 7) stage(ch + 1, (ch + 1) & 1);
        const unsigned int* cb = sseq[ch & 1];
#pragma unroll
        for (int kk = 0; kk < 2; ++kk) {
            short8 bfr[8];
#pragma unroll
            for (int s = 0; s < 8; ++s) {
                int n = s * 16 + mm;
                int g = kk * 4 + q;
                int sw = (n ^ (n >> 3)) & 7;
                bfr[s] = *(const short8*)(cb + n * 32 + ((g ^ sw) << 2));
            }
#pragma unroll
            for (int s = 0; s < 8; ++s)
                acc[s] = __builtin_amdgcn_mfma_f32_16x16x32_bf16(
                    afrag[ch * 2 + kk], bfr[s], acc[s], 0, 0, 0);
        }
        __syncthreads();
    }

    const float invsqrtk = 0.036084391824351615f;
#pragma unroll
    for (int reg = 0; reg < 4; ++reg) {
        int row = q * 4 + reg;
        int rr = rt * 64 + wv * 16 + row;
        if (rr < 196) {
            float scale = sinvz[wv * 16 + row] * invsqrtk;
            float* op = out + (size_t)(b * 196 + rr) * 768 + nb + mm;
#pragma unroll
            for (int s = 0; s < 8; ++s)
                op[s * 16] = acc[s][reg] * scale;
        }
    }
}

extern "C" void kernel_launch(void* const* d_in, const int* in_sizes, int n_in,
                              void* d_out, int out_size, void* d_ws, size_t ws_size,
                              hipStream_t stream) {
    const float* image_emb = (const float*)d_in[0];
    const float* seq_emb   = (const float*)d_in[1];
    const int*   mask      = (const int*)d_in[2];
    const float* image_W   = (const float*)d_in[3];
    const float* image_b   = (const float*)d_in[4];
    const float* seq_W     = (const float*)d_in[5];
    const float* seq_b     = (const float*)d_in[6];
    const float* V         = (const float*)d_in[7];
    float* out = (float*)d_out;

    float* p_ws  = (float*)d_ws;                             // 12544 f
    float* q_ws  = (float*)((char*)d_ws + (64 << 10));       // 32768 f
    float* wm_ws = (float*)((char*)d_ws + (192 << 10));      // 32768 f
    unsigned short* seqT = (unsigned short*)((char*)d_ws + (384 << 10));  // 64*768*512 bf16

    size_t need = (size_t)(384 << 10) + (size_t)64 * 768 * 512 * 2;
    if (ws_size >= need) {
        kprep<<<dim3(3648), dim3(256), 0, stream>>>(seq_emb, seq_W, seq_b,
                                                    image_emb, image_W, image_b,
                                                    seqT, q_ws, p_ws);
        kw<<<dim3(256), dim3(256), 0, stream>>>(q_ws, V, mask, wm_ws);
        kattn2<<<dim3(1536), dim3(256), 0, stream>>>(seqT, p_ws, wm_ws, out);
    } else {
        krows_p<<<dim3(3136), dim3(256), 0, stream>>>(image_emb, image_W, image_b, p_ws);
        krows_q<<<dim3(8192), dim3(256), 0, stream>>>(seq_emb, seq_W, seq_b, q_ws);
        kw<<<dim3(256), dim3(256), 0, stream>>>(q_ws, V, mask, wm_ws);
        kattn<<<dim3(1536), dim3(256), 0, stream>>>(seq_emb, p_ws, wm_ws, out);
    }
}

// Round 4
// 233.411 us; speedup vs baseline: 1.1036x; 1.0243x over previous
//
#include <hip/hip_runtime.h>
#include <cstdint>
#include <cstddef>

// Problem: B=64, R=196, L=512, K=768.
// Algebra: emb = p @ q^T + q^T = (1+p) outer q ==>
//   score[b,r,j] = (1+p[b,r]) * w[b,j],  w[b,:] = q[b,:] @ V
// out[b,r,:] = (1/Z_r) * sum_j exp(c_r*wm_j - M_r) * seq_emb[b,j,:] / sqrt(768)
//
// Round-4: kprep transpose split over (b,jt,ck)=3072 blocks (R3 was 512 blocks
// with a serial 6-chunk loop -> latency-bound, Occ 33%, VALU 8%). q partial
// dots accumulate via atomicAdd into memset-zeroed buffer; tanh moved to kw.

typedef __attribute__((ext_vector_type(8))) short short8;
typedef __attribute__((ext_vector_type(4))) float f32x4;

__device__ __forceinline__ unsigned short f32_to_bf16(float x) {
    unsigned int u = __float_as_uint(x);
    unsigned int r = (u + 0x7FFFu + ((u >> 16) & 1u)) >> 16;  // RNE
    return (unsigned short)r;
}
__device__ __forceinline__ float bf16_to_f32(unsigned short h) {
    return __uint_as_float(((unsigned int)h) << 16);
}

#if defined(__has_builtin)
#if __has_builtin(__builtin_amdgcn_cvt_pk_bf16_f32)
#define HAVE_PK_BF16 1
#endif
#endif

__device__ __forceinline__ unsigned int pk_bf16(float a, float b) {
#ifdef HAVE_PK_BF16
    typedef __attribute__((ext_vector_type(2))) __bf16 bf16x2;
    bf16x2 v = __builtin_amdgcn_cvt_pk_bf16_f32(a, b);
    return __builtin_bit_cast(unsigned int, v);
#else
    return (unsigned int)f32_to_bf16(a) | ((unsigned int)f32_to_bf16(b) << 16);
#endif
}

// ---- kernel 1: blocks 0..3071 transpose one 64j x 128k tile (+q partials);
//      blocks 3072..6207 compute p rows.
__global__ __launch_bounds__(256) void kprep(const float* __restrict__ seq,
                                             const float* __restrict__ seqW,
                                             const float* __restrict__ img,
                                             const float* __restrict__ imgW,
                                             const float* __restrict__ imgBias,
                                             unsigned short* __restrict__ seqT,
                                             float* __restrict__ qacc,
                                             float* __restrict__ pv) {
    __shared__ __align__(16) unsigned int sT[128 * 32];   // [k][16 j-quads x 2 u32]
    __shared__ __align__(16) float sWc[128];

    if (blockIdx.x >= 3072) {
        // ---- p[row] = tanh(image_emb[row,:512] . image_W) ----
        int wv = threadIdx.x >> 6, lane = threadIdx.x & 63;
        int row = (blockIdx.x - 3072) * 4 + wv;           // 12544 rows
        const float4* x4 = (const float4*)(img + (size_t)row * 512);
        const float4* w4 = (const float4*)imgW;
        float s = 0.f;
#pragma unroll
        for (int i = 0; i < 2; ++i) {
            float4 a = x4[i * 64 + lane];
            float4 c = w4[i * 64 + lane];
            s += a.x * c.x + a.y * c.y + a.z * c.z + a.w * c.w;
        }
#pragma unroll
        for (int o = 32; o; o >>= 1) s += __shfl_xor(s, o, 64);
        if (lane == 0) pv[row] = tanhf(s + imgBias[0]);
        return;
    }

    // ---- transpose tile: block = (b, jt, ck) ----
    int id = blockIdx.x;
    int b = id / 48, rem = id - b * 48;
    int jt = rem / 6, ck = rem - jt * 6;
    int j0 = jt * 64;
    int t = threadIdx.x;
    if (t < 128) sWc[t] = seqW[ck * 128 + t];

    int quad = t >> 4, kseg = t & 15;                     // 4 j-rows x (2x4) k
    int qk = quad ^ kseg;
    const float* base = seq + (size_t)b * 512 * 768 + (size_t)(j0 + quad * 4) * 768 + ck * 128;
    int jg = t & 7, krow = t >> 3;                        // readout: 8 j x b128
    float qp[4] = {0.f, 0.f, 0.f, 0.f};
    __syncthreads();

#pragma unroll
    for (int rp = 0; rp < 2; ++rp) {
        int kq = rp * 64 + kseg * 4;                      // local k 0..124
        float4 r0 = *(const float4*)(base + 0 * 768 + kq);
        float4 r1 = *(const float4*)(base + 1 * 768 + kq);
        float4 r2 = *(const float4*)(base + 2 * 768 + kq);
        float4 r3 = *(const float4*)(base + 3 * 768 + kq);
        float4 w  = *(const float4*)(sWc + kq);
        qp[0] += r0.x * w.x + r0.y * w.y + r0.z * w.z + r0.w * w.w;
        qp[1] += r1.x * w.x + r1.y * w.y + r1.z * w.z + r1.w * w.w;
        qp[2] += r2.x * w.x + r2.y * w.y + r2.z * w.z + r2.w * w.w;
        qp[3] += r3.x * w.x + r3.y * w.y + r3.z * w.z + r3.w * w.w;
        float a0[4] = {r0.x, r0.y, r0.z, r0.w};
        float a1[4] = {r1.x, r1.y, r1.z, r1.w};
        float a2[4] = {r2.x, r2.y, r2.z, r2.w};
        float a3[4] = {r3.x, r3.y, r3.z, r3.w};
#pragma unroll
        for (int i = 0; i < 4; ++i) {
            int k = kq + i;
            int col = (qk ^ (i << 2)) & 15;
            uint2 v;
            v.x = pk_bf16(a0[i], a1[i]);
            v.y = pk_bf16(a2[i], a3[i]);
            *(uint2*)(sT + k * 32 + col * 2) = v;
        }
    }
    __syncthreads();
    unsigned short* dst = seqT + (size_t)b * 768 * 512 + (size_t)ck * 128 * 512 + j0;
#pragma unroll
    for (int wp = 0; wp < 4; ++wp) {
        int k = wp * 32 + krow;
        int s = ((k >> 2) & 15) ^ ((k & 3) << 2);
        int c0 = ((jg << 1) ^ s) & 15;
        int c1 = ((jg << 1) ^ 1 ^ s) & 15;
        uint2 va = *(const uint2*)(sT + k * 32 + c0 * 2);
        uint2 vb = *(const uint2*)(sT + k * 32 + c1 * 2);
        uint4 o;
        o.x = va.x; o.y = va.y; o.z = vb.x; o.w = vb.y;
        *(uint4*)(dst + (size_t)k * 512 + jg * 8) = o;
    }
    // q partial dots -> atomic accumulate (raw, pre-bias/tanh)
#pragma unroll
    for (int rr = 0; rr < 4; ++rr) {
        float s = qp[rr];
        s += __shfl_xor(s, 8, 64);
        s += __shfl_xor(s, 4, 64);
        s += __shfl_xor(s, 2, 64);
        s += __shfl_xor(s, 1, 64);
        if (kseg == 0) atomicAdd(qacc + b * 512 + j0 + quad * 4 + rr, s);
    }
}

// ---------------- fallback: p rows standalone -------------------------------
__global__ __launch_bounds__(256) void krows_p(const float* __restrict__ x,
                                               const float* __restrict__ w,
                                               const float* __restrict__ bias,
                                               float* __restrict__ outp) {
    int wv = threadIdx.x >> 6, lane = threadIdx.x & 63;
    int row = blockIdx.x * 4 + wv;
    const float4* x4 = (const float4*)(x + (size_t)row * 512);
    const float4* w4 = (const float4*)w;
    float s = 0.f;
#pragma unroll
    for (int i = 0; i < 2; ++i) {
        float4 a = x4[i * 64 + lane];
        float4 c = w4[i * 64 + lane];
        s += a.x * c.x + a.y * c.y + a.z * c.z + a.w * c.w;
    }
#pragma unroll
    for (int o = 32; o; o >>= 1) s += __shfl_xor(s, o, 64);
    if (lane == 0) outp[row] = tanhf(s + bias[0]);
}

// ---------------- fallback: q rows standalone (raw dot, no bias/tanh) -------
__global__ __launch_bounds__(256) void krows_q(const float* __restrict__ x,
                                               const float* __restrict__ w,
                                               float* __restrict__ outp) {
    int wv = threadIdx.x >> 6, lane = threadIdx.x & 63;
    int row = blockIdx.x * 4 + wv;
    const float4* x4 = (const float4*)(x + (size_t)row * 768);
    const float4* w4 = (const float4*)w;
    float s = 0.f;
#pragma unroll
    for (int i = 0; i < 3; ++i) {
        float4 a = x4[i * 64 + lane];
        float4 c = w4[i * 64 + lane];
        s += a.x * c.x + a.y * c.y + a.z * c.z + a.w * c.w;
    }
#pragma unroll
    for (int o = 32; o; o >>= 1) s += __shfl_xor(s, o, 64);
    if (lane == 0) outp[row] = s;
}

// ------- kernel 3: wm[b,j] = mask ? (tanh(qacc+b) @ V[:,j]) : -1e30 ---------
__global__ __launch_bounds__(256) void kw(const float* __restrict__ qacc,
                                          const float* __restrict__ seqBias,
                                          const float* __restrict__ V,
                                          const int* __restrict__ mask,
                                          float* __restrict__ wm) {
    __shared__ __align__(16) float sq[512];
    __shared__ __align__(16) float sacc[8][32][4];
    int b = blockIdx.x >> 2, jc = blockIdx.x & 3;
    int t = threadIdx.x;
    float qb = seqBias[0];
    sq[t] = tanhf(qacc[b * 512 + t] + qb);
    sq[t + 256] = tanhf(qacc[b * 512 + t + 256] + qb);
    __syncthreads();
    int jt = t & 31, lg = t >> 5;
    const float4* V4 = (const float4*)V;
    int col4 = jc * 32 + jt;
    float ax = 0.f, ay = 0.f, az = 0.f, aw = 0.f;
    int lbase = lg * 64;
#pragma unroll 8
    for (int li = 0; li < 64; ++li) {
        int l = lbase + li;
        float qq = sq[l];
        float4 v = V4[(size_t)l * 128 + col4];
        ax += qq * v.x; ay += qq * v.y; az += qq * v.z; aw += qq * v.w;
    }
    sacc[lg][jt][0] = ax; sacc[lg][jt][1] = ay;
    sacc[lg][jt][2] = az; sacc[lg][jt][3] = aw;
    __syncthreads();
    if (t < 32) {
        float sx = 0.f, sy = 0.f, sz = 0.f, sw = 0.f;
#pragma unroll
        for (int g = 0; g < 8; ++g) {
            sx += sacc[g][t][0]; sy += sacc[g][t][1];
            sz += sacc[g][t][2]; sw += sacc[g][t][3];
        }
        const int* mrow = mask + b * 512 + jc * 128 + t * 4;
        float4 o;
        o.x = mrow[0] ? sx : -1e30f;
        o.y = mrow[1] ? sy : -1e30f;
        o.z = mrow[2] ? sz : -1e30f;
        o.w = mrow[3] ? sw : -1e30f;
        ((float4*)(wm + b * 512 + jc * 128))[t] = o;
    }
}

// ------- kernel 4: softmax-weights (regs) x seqT bf16 tile (LDS) ------------
__global__ __launch_bounds__(256, 2) void kattn2(const unsigned short* __restrict__ seqT,
                                                 const float* __restrict__ p,
                                                 const float* __restrict__ wm,
                                                 float* __restrict__ out) {
    __shared__ __align__(16) unsigned short sB[2][128 * 64];  // 2 x 16 KB
    __shared__ __align__(16) float swm[512];
    __shared__ float sinvz[64];
    __shared__ float sred[16];

    int raw = blockIdx.x;
    int g  = ((raw >> 5) << 3) + (raw & 7);           // 0..383 = (b,nt)
    int rt = (raw >> 3) & 3;
    int b  = g / 6, nt = g - b * 6;
    int t  = threadIdx.x;
    int wv = t >> 6, lane = t & 63;
    int mm = lane & 15, q = lane >> 4;
    int nb = nt * 128;

    float v0 = wm[b * 512 + t];
    float v1 = wm[b * 512 + t + 256];
    swm[t] = v0; swm[t + 256] = v1;
    float lmax = fmaxf(v0, v1);
    float fa = (v0 > -1e29f) ? v0 : 1e30f;
    float fb = (v1 > -1e29f) ? v1 : 1e30f;
    float lmin = fminf(fa, fb);
#pragma unroll
    for (int o = 32; o; o >>= 1) {
        lmax = fmaxf(lmax, __shfl_xor(lmax, o, 64));
        lmin = fminf(lmin, __shfl_xor(lmin, o, 64));
    }
    if (lane == 0) { sred[wv] = lmax; sred[8 + wv] = lmin; }
    __syncthreads();
    float wmax = fmaxf(fmaxf(sred[0], sred[1]), fmaxf(sred[2], sred[3]));
    float wmin = fminf(fminf(sred[8], sred[9]), fminf(sred[10], sred[11]));

    int rl = wv * 16 + mm;
    int r  = rt * 64 + rl;
    bool valid = r < 196;
    int pidx = b * 196 + (valid ? r : 195);
    float c = 1.0f + p[pidx];
    float M = (c >= 0.f) ? c * wmax : c * wmin;

    short8 afrag[16];
    float zsum = 0.f;
    const f32x4* swm4 = (const f32x4*)swm;
#pragma unroll
    for (int tk = 0; tk < 16; ++tk) {
        int jb = tk * 32 + q * 8;
        f32x4 w0 = swm4[jb >> 2];
        f32x4 w1 = swm4[(jb >> 2) + 1];
        short8 af;
#pragma unroll
        for (int jj = 0; jj < 8; ++jj) {
            float ww = (jj < 4) ? w0[jj] : w1[jj - 4];
            float e = valid ? __expf(c * ww - M) : 0.f;
            unsigned short h = f32_to_bf16(e);
            zsum += bf16_to_f32(h);
            af[jj] = (short)h;
        }
        afrag[tk] = af;
    }
    zsum += __shfl_xor(zsum, 16, 64);
    zsum += __shfl_xor(zsum, 32, 64);
    if (q == 0) sinvz[rl] = 1.0f / zsum;

    f32x4 acc[8];
#pragma unroll
    for (int s = 0; s < 8; ++s) acc[s] = (f32x4){0.f, 0.f, 0.f, 0.f};

    const unsigned short* seqTb = seqT + (size_t)b * 768 * 512 + (size_t)nb * 512;
    int nrow = t >> 3, jg = t & 7;
    auto stage = [&](int ch, int buf) {
        unsigned short* sb = sB[buf];
#pragma unroll
        for (int pp = 0; pp < 4; ++pp) {
            int n = pp * 32 + nrow;
            short8 v = *(const short8*)(seqTb + (size_t)n * 512 + ch * 64 + jg * 8);
            int sw = (n ^ (n >> 3)) & 7;
            *(short8*)(sb + n * 64 + ((jg ^ sw) << 3)) = v;
        }
    };

    __syncthreads();
    stage(0, 0);
    __syncthreads();
#pragma unroll
    for (int ch = 0; ch < 8; ++ch) {
        if (ch < 7) stage(ch + 1, (ch + 1) & 1);
        const unsigned short* cb = sB[ch & 1];
#pragma unroll
        for (int kk = 0; kk < 2; ++kk) {
            short8 bfr[8];
#pragma unroll
            for (int s = 0; s < 8; ++s) {
                int n = s * 16 + mm;
                int sw = (n ^ (n >> 3)) & 7;
                bfr[s] = *(const short8*)(cb + n * 64 + ((((kk << 2) + q) ^ sw) << 3));
            }
#pragma unroll
            for (int s = 0; s < 8; ++s)
                acc[s] = __builtin_amdgcn_mfma_f32_16x16x32_bf16(
                    afrag[(ch << 1) + kk], bfr[s], acc[s], 0, 0, 0);
        }
        __syncthreads();
    }

    const float invsqrtk = 0.036084391824351615f;
#pragma unroll
    for (int reg = 0; reg < 4; ++reg) {
        int row = q * 4 + reg;
        int rr = rt * 64 + wv * 16 + row;
        if (rr < 196) {
            float scale = sinvz[wv * 16 + row] * invsqrtk;
            float* op = out + (size_t)(b * 196 + rr) * 768 + nb + mm;
#pragma unroll
            for (int s = 0; s < 8; ++s)
                op[s * 16] = acc[s][reg] * scale;
        }
    }
}

// ------- fallback kernel 4 (fp32-source staging, round-1) -------------------
__global__ __launch_bounds__(256, 2) void kattn(const float* __restrict__ seq,
                                                const float* __restrict__ p,
                                                const float* __restrict__ wm,
                                                float* __restrict__ out) {
    __shared__ __align__(16) unsigned int sseq[2][128 * 32];
    __shared__ __align__(16) float swm[512];
    __shared__ float sinvz[64];
    __shared__ float sred[16];

    int id = blockIdx.x;
    int rt = id & 3;
    int nt = (id >> 2) % 6;
    int b  = id / 24;
    int t  = threadIdx.x;
    int wv = t >> 6, lane = t & 63;
    int mm = lane & 15, q = lane >> 4;
    int nb = nt * 128;

    float v0 = wm[b * 512 + t];
    float v1 = wm[b * 512 + t + 256];
    swm[t] = v0; swm[t + 256] = v1;
    float lmax = fmaxf(v0, v1);
    float fa = (v0 > -1e29f) ? v0 : 1e30f;
    float fb = (v1 > -1e29f) ? v1 : 1e30f;
    float lmin = fminf(fa, fb);
#pragma unroll
    for (int o = 32; o; o >>= 1) {
        lmax = fmaxf(lmax, __shfl_xor(lmax, o, 64));
        lmin = fminf(lmin, __shfl_xor(lmin, o, 64));
    }
    if (lane == 0) { sred[wv] = lmax; sred[8 + wv] = lmin; }
    __syncthreads();
    float wmax = fmaxf(fmaxf(sred[0], sred[1]), fmaxf(sred[2], sred[3]));
    float wmin = fminf(fminf(sred[8], sred[9]), fminf(sred[10], sred[11]));

    int rl = wv * 16 + mm;
    int r  = rt * 64 + rl;
    bool valid = r < 196;
    int pidx = b * 196 + (valid ? r : 195);
    float c = 1.0f + p[pidx];
    float M = (c >= 0.f) ? c * wmax : c * wmin;

    short8 afrag[16];
    float zsum = 0.f;
    const f32x4* swm4 = (const f32x4*)swm;
#pragma unroll
    for (int tk = 0; tk < 16; ++tk) {
        int jb = tk * 32 + q * 8;
        f32x4 w0 = swm4[jb >> 2];
        f32x4 w1 = swm4[(jb >> 2) + 1];
        short8 af;
#pragma unroll
        for (int jj = 0; jj < 8; ++jj) {
            float ww = (jj < 4) ? w0[jj] : w1[jj - 4];
            float e = valid ? __expf(c * ww - M) : 0.f;
            unsigned short h = f32_to_bf16(e);
            zsum += bf16_to_f32(h);
            af[jj] = (short)h;
        }
        afrag[tk] = af;
    }
    zsum += __shfl_xor(zsum, 16, 64);
    zsum += __shfl_xor(zsum, 32, 64);
    if (q == 0) sinvz[rl] = 1.0f / zsum;

    f32x4 acc[8];
#pragma unroll
    for (int s = 0; s < 8; ++s) acc[s] = (f32x4){0.f, 0.f, 0.f, 0.f};

    const float* seqb = seq + (size_t)b * 512 * 768 + nb;
    int tl = t & 31, jp = t >> 5;
    int n0 = tl * 4;
    auto stage = [&](int ch, int buf) {
        unsigned int* sb = sseq[buf];
#pragma unroll
        for (int pass = 0; pass < 4; ++pass) {
            int jl = pass * 16 + jp * 2;
            int jglob = ch * 64 + jl;
            float4 a0 = *(const float4*)(seqb + (size_t)jglob * 768 + n0);
            float4 a1 = *(const float4*)(seqb + (size_t)(jglob + 1) * 768 + n0);
            float a0v[4] = {a0.x, a0.y, a0.z, a0.w};
            float a1v[4] = {a1.x, a1.y, a1.z, a1.w};
            int g = jl >> 3;
            int wo = (jl & 7) >> 1;
#pragma unroll
            for (int i = 0; i < 4; ++i) {
                int n = n0 + i;
                int sw = (n ^ (n >> 3)) & 7;
                unsigned int pk = (unsigned int)f32_to_bf16(a0v[i]) |
                                  ((unsigned int)f32_to_bf16(a1v[i]) << 16);
                sb[n * 32 + ((g ^ sw) << 2) + wo] = pk;
            }
        }
    };

    __syncthreads();
    stage(0, 0);
    __syncthreads();
#pragma unroll
    for (int ch = 0; ch < 8; ++ch) {
        if (ch < 7) stage(ch + 1, (ch + 1) & 1);
        const unsigned int* cb = sseq[ch & 1];
#pragma unroll
        for (int kk = 0; kk < 2; ++kk) {
            short8 bfr[8];
#pragma unroll
            for (int s = 0; s < 8; ++s) {
                int n = s * 16 + mm;
                int g = kk * 4 + q;
                int sw = (n ^ (n >> 3)) & 7;
                bfr[s] = *(const short8*)(cb + n * 32 + ((g ^ sw) << 2));
            }
#pragma unroll
            for (int s = 0; s < 8; ++s)
                acc[s] = __builtin_amdgcn_mfma_f32_16x16x32_bf16(
                    afrag[ch * 2 + kk], bfr[s], acc[s], 0, 0, 0);
        }
        __syncthreads();
    }

    const float invsqrtk = 0.036084391824351615f;
#pragma unroll
    for (int reg = 0; reg < 4; ++reg) {
        int row = q * 4 + reg;
        int rr = rt * 64 + wv * 16 + row;
        if (rr < 196) {
            float scale = sinvz[wv * 16 + row] * invsqrtk;
            float* op = out + (size_t)(b * 196 + rr) * 768 + nb + mm;
#pragma unroll
            for (int s = 0; s < 8; ++s)
                op[s * 16] = acc[s][reg] * scale;
        }
    }
}

extern "C" void kernel_launch(void* const* d_in, const int* in_sizes, int n_in,
                              void* d_out, int out_size, void* d_ws, size_t ws_size,
                              hipStream_t stream) {
    const float* image_emb = (const float*)d_in[0];
    const float* seq_emb   = (const float*)d_in[1];
    const int*   mask      = (const int*)d_in[2];
    const float* image_W   = (const float*)d_in[3];
    const float* image_b   = (const float*)d_in[4];
    const float* seq_W     = (const float*)d_in[5];
    const float* seq_b     = (const float*)d_in[6];
    const float* V         = (const float*)d_in[7];
    float* out = (float*)d_out;

    float* p_ws  = (float*)d_ws;                             // 12544 f
    float* q_ws  = (float*)((char*)d_ws + (64 << 10));       // 32768 f
    float* wm_ws = (float*)((char*)d_ws + (192 << 10));      // 32768 f
    unsigned short* seqT = (unsigned short*)((char*)d_ws + (384 << 10));  // 64*768*512 bf16

    size_t need = (size_t)(384 << 10) + (size_t)64 * 768 * 512 * 2;
    if (ws_size >= need) {
        hipMemsetAsync(q_ws, 0, 512 * 64 * sizeof(float), stream);
        kprep<<<dim3(6208), dim3(256), 0, stream>>>(seq_emb, seq_W,
                                                    image_emb, image_W, image_b,
                                                    seqT, q_ws, p_ws);
        kw<<<dim3(256), dim3(256), 0, stream>>>(q_ws, seq_b, V, mask, wm_ws);
        kattn2<<<dim3(1536), dim3(256), 0, stream>>>(seqT, p_ws, wm_ws, out);
    } else {
        krows_p<<<dim3(3136), dim3(256), 0, stream>>>(image_emb, image_W, image_b, p_ws);
        krows_q<<<dim3(8192), dim3(256), 0, stream>>>(seq_emb, seq_W, q_ws);
        kw<<<dim3(256), dim3(256), 0, stream>>>(q_ws, seq_b, V, mask, wm_ws);
        kattn<<<dim3(1536), dim3(256), 0, stream>>>(seq_emb, p_ws, wm_ws, out);
    }
}